// Round 6
// baseline (302.573 us; speedup 1.0000x reference)
//
#include <hip/hip_runtime.h>
#include <stdint.h>

// ---------------------------------------------------------------------------
// HaloAttn: BLOCK=8, HALO=3, WIN=14, NH=8, DH=32, DIM=256, DV=256
// fp32 in/out; internal bf16 MFMA.
// kv channel c = head*64 + r : r<32 -> K, r>=32 -> V   (reference reshape!)
// Key tiling (k_attn): key' = i*16 + j  (i=0..13 row tiles, j=0..15, j>=14 masked)
// ---------------------------------------------------------------------------

typedef short bf16s;                                      // raw bf16 storage
typedef bf16s bf16x8 __attribute__((ext_vector_type(8))); // MFMA A/B frag
typedef float f32x4  __attribute__((ext_vector_type(4))); // MFMA C/D frag
typedef unsigned int u32x4 __attribute__((ext_vector_type(4)));

#define MFMA16(a, b, c) __builtin_amdgcn_mfma_f32_16x16x32_bf16(a, b, c, 0, 0, 0)
#define SCALE_QK 0.17677669529663687f
#define LOG2E 1.4426950408889634f
#define EXP_SHIFT 11.541560327111707f   // 8 * log2(e)

__device__ __forceinline__ void async16(void* lds, const void* g) {
  __builtin_amdgcn_global_load_lds(
      (const __attribute__((address_space(1))) unsigned int*)g,
      (__attribute__((address_space(3))) unsigned int*)lds, 16, 0, 0);
}

__device__ __forceinline__ bf16s f2b(float f) {
  unsigned int u = __builtin_bit_cast(unsigned int, f);
  u = (u + 0x7fffu + ((u >> 16) & 1u)) >> 16;
  return (bf16s)u;
}

// ---------------------------------------------------------------------------
// K_convert: fp32 -> bf16 weights + rel tables ([relid][32r][32d], rows>=27=0)
// ---------------------------------------------------------------------------
__global__ __launch_bounds__(256) void k_convert(const float* __restrict__ wq,
                                                 const float* __restrict__ wkv,
                                                 const float* __restrict__ hrel,
                                                 const float* __restrict__ wrel,
                                                 bf16s* __restrict__ wq_b,
                                                 bf16s* __restrict__ wkv_b,
                                                 bf16s* __restrict__ rel_b) {
  int i = blockIdx.x * 256 + threadIdx.x;   // grid 776 * 256 = 198656 exact
  if (i < 65536) {
    wq_b[i] = f2b(wq[i]);
  } else if (i < 196608) {
    int j = i - 65536;
    wkv_b[j] = f2b(wkv[j]);
  } else {
    int r2 = i - 196608;                    // [0,2048)
    int relid = r2 >> 10, r = (r2 >> 5) & 31, d = r2 & 31;
    const float* src = relid ? hrel : wrel;
    rel_b[r2] = (r < 27) ? f2b(src[r * 32 + d]) : (bf16s)0;
  }
}

// ---------------------------------------------------------------------------
// K0: x fp32 (b,c,p) -> xT bf16 (b,p,c)
// ---------------------------------------------------------------------------
__global__ __launch_bounds__(256) void k_transpose(const float* __restrict__ x,
                                                   bf16s* __restrict__ xT) {
  __shared__ bf16s tile[64][72];
  const int ct = blockIdx.x, pt = blockIdx.y, b = blockIdx.z;
  const int t = threadIdx.x;
  const int r0 = t >> 3, c8 = (t & 7) * 8;
  const float* src = x + ((size_t)b * 256 + ct * 64) * 16384 + (size_t)pt * 64;
#pragma unroll
  for (int pass = 0; pass < 2; ++pass) {
    int r = pass * 32 + r0;
    const float4* sp = (const float4*)(src + (size_t)r * 16384 + c8);
    float4 f0 = sp[0], f1 = sp[1];
    bf16x8 v;
    v[0] = f2b(f0.x); v[1] = f2b(f0.y); v[2] = f2b(f0.z); v[3] = f2b(f0.w);
    v[4] = f2b(f1.x); v[5] = f2b(f1.y); v[6] = f2b(f1.z); v[7] = f2b(f1.w);
    *(bf16x8*)&tile[r][c8] = v;
  }
  __syncthreads();
  bf16s* dst = xT + ((size_t)b * 16384 + pt * 64) * 256 + ct * 64;
#pragma unroll
  for (int pass = 0; pass < 2; ++pass) {
    int p = pass * 32 + r0;
    bf16x8 v;
#pragma unroll
    for (int u = 0; u < 8; ++u) v[u] = tile[c8 + u][p];
    *(bf16x8*)(dst + (size_t)p * 256 + c8) = v;
  }
}

// ---------------------------------------------------------------------------
// K0b: zero halo borders.
//  K:  [b][134][134][256]      border pixels (y or x in {0,1,2,131,132,133})
//  V^T:[1024 planes][134][144] rows {0,1,2,131,132,133} full; cols x' in
//      {8,9,10} u {139,140,141} for y' 3..130.
// grid 2242 * 256 = 573952 exact (201216 K + 110592 Vrows + 262144 Vcols)
// ---------------------------------------------------------------------------
__global__ __launch_bounds__(256) void k_zero_border(bf16s* __restrict__ kvK,
                                                     bf16s* __restrict__ vws) {
  const int gid = blockIdx.x * 256 + threadIdx.x;
  u32x4 z = {0, 0, 0, 0};
  if (gid < 201216) {                 // K border: 6288 px * 32 chunks
    int chunk = gid & 31;
    int pxid = gid >> 5;
    int b = pxid / 1572, pxi = pxid % 1572;
    int y, x;
    if (pxi < 804) {
      int r = pxi / 134;
      x = pxi % 134;
      y = (r < 3) ? r : 128 + r;
    } else {
      int p2 = pxi - 804;
      y = 3 + p2 / 6;
      int xi = p2 % 6;
      x = (xi < 3) ? xi : 128 + xi;
    }
    *(u32x4*)(kvK + (((size_t)b * 134 + y) * 134 + x) * 256 + chunk * 8) = z;
  } else if (gid < 311808) {          // V^T rows: 1024 planes * 6 rows * 18 b128
    int idx = gid - 201216;
    int plane = idx / 108, r = idx - plane * 108;
    int row6 = r / 18, c8 = (r - row6 * 18) * 8;
    int y = (row6 < 3) ? row6 : 128 + row6;
    *(u32x4*)(vws + ((size_t)plane * 134 + y) * 144 + c8) = z;
  } else {                            // V^T cols: 1024 planes * 128 rows * 2
    int idx = gid - 311808;
    int plane = idx >> 8, r = idx & 255;
    int y = 3 + (r >> 1);
    bf16s* row = vws + ((size_t)plane * 134 + y) * 144;
    if (r & 1) { row[139] = 0; *(unsigned int*)(row + 140) = 0; }
    else       { *(unsigned int*)(row + 8) = 0; row[10] = 0; }
  }
}

// ---------------------------------------------------------------------------
// K1: qkv projection GEMM.  C[o][p] = sum_c W[o][c] * xT[b][p][c]
// mt 0,1 -> q_ws [bh][blk][qpos][32]
// mt 2..5 -> kv tile = heads 2*(mt-2), 2*(mt-2)+1:
//   o_local {0..31, 64..95}   = K -> kv_K [b][y+3][x+3][head*32+d]
//   o_local {32..63, 96..127} = V -> V^T  [plane=(b*8+h)*32+d][y+3][x+11]
// ---------------------------------------------------------------------------
__global__ __launch_bounds__(256) void k_qkv(const bf16s* __restrict__ wq,
                                             const bf16s* __restrict__ wkv,
                                             const bf16s* __restrict__ xT,
                                             bf16s* __restrict__ q_ws,
                                             bf16s* __restrict__ kv_K,
                                             bf16s* __restrict__ v_ws) {
  __shared__ __align__(16) bf16s smem[17408];  // A:4096|B:4096 ; epi Cl/ClV
  bf16s* Al = smem;
  bf16s* Bl = smem + 4096;
  const int mt = blockIdx.x, y = blockIdx.y, b = blockIdx.z;
  const int t = threadIdx.x;
  const int wv = t >> 6, lane = t & 63, g = lane >> 4, l15 = lane & 15;
  const int wm = wv & 1, wn = wv >> 1;
  const bf16s* Ag = (mt < 2) ? (wq + mt * 128 * 256) : (wkv + (mt - 2) * 128 * 256);
  const bf16s* Bg = xT + ((size_t)b * 16384 + y * 128) * 256;

  f32x4 acc[4][4];
#pragma unroll
  for (int i = 0; i < 4; ++i)
#pragma unroll
    for (int j = 0; j < 4; ++j) acc[i][j] = (f32x4){0.f, 0.f, 0.f, 0.f};

  for (int kc = 0; kc < 8; ++kc) {
    __syncthreads();
#pragma unroll
    for (int hh = 0; hh < 2; ++hh) {
      int tt = hh * 256 + t;
      int row = tt >> 2, k8 = (tt & 3) * 8;
      async16((char*)Al + hh * 4096 + wv * 1024, Ag + row * 256 + kc * 32 + k8);
      async16((char*)Bl + hh * 4096 + wv * 1024, Bg + row * 256 + kc * 32 + k8);
    }
    __syncthreads();
    bf16x8 af[4], bfr[4];
#pragma unroll
    for (int mi = 0; mi < 4; ++mi)
      af[mi] = *(const bf16x8*)&Al[(wm * 64 + mi * 16 + l15) * 32 + g * 8];
#pragma unroll
    for (int ni = 0; ni < 4; ++ni)
      bfr[ni] = *(const bf16x8*)&Bl[(wn * 64 + ni * 16 + l15) * 32 + g * 8];
#pragma unroll
    for (int mi = 0; mi < 4; ++mi)
#pragma unroll
      for (int ni = 0; ni < 4; ++ni)
        acc[mi][ni] = MFMA16(af[mi], bfr[ni], acc[mi][ni]);
  }

  __syncthreads();
  if (mt < 2) {
    bf16s* Cl = smem;  // [px 128][o 128], stride 136
#pragma unroll
    for (int mi = 0; mi < 4; ++mi)
#pragma unroll
      for (int ni = 0; ni < 4; ++ni)
#pragma unroll
        for (int rg = 0; rg < 4; ++rg) {
          int m = wm * 64 + mi * 16 + g * 4 + rg;
          int n = wn * 64 + ni * 16 + l15;
          Cl[n * 136 + m] = f2b(acc[mi][ni][rg]);
        }
    __syncthreads();
#pragma unroll
    for (int hh = 0; hh < 2; ++hh) {
      int rid = hh * 256 + t;
      int head = rid >> 7, bx = (rid >> 3) & 15, wc = rid & 7;
      int px = bx * 8 + wc;
      bf16s* dst = q_ws +
          ((((size_t)(b * 8 + mt * 4 + head) * 256 + (y >> 3) * 16 + bx) * 64 +
            (y & 7) * 8 + wc)) * 32;
#pragma unroll
      for (int c4 = 0; c4 < 4; ++c4)
        *(bf16x8*)(dst + c4 * 8) = *(const bf16x8*)&Cl[px * 136 + head * 32 + c4 * 8];
    }
  } else {
    // ---- Pass A: Cl [px][o] -> K channel-last ----
    bf16s* Cl = smem;  // stride 136
#pragma unroll
    for (int mi = 0; mi < 4; ++mi)
#pragma unroll
      for (int ni = 0; ni < 4; ++ni)
#pragma unroll
        for (int rg = 0; rg < 4; ++rg) {
          int m = wm * 64 + mi * 16 + g * 4 + rg;
          int n = wn * 64 + ni * 16 + l15;
          Cl[n * 136 + m] = f2b(acc[mi][ni][rg]);
        }
    __syncthreads();
    {
      int px = t >> 1, sel = t & 1;           // sel: which head of the pair
      int head = 2 * (mt - 2) + sel;
      bf16s* dst = kv_K + (((size_t)b * 134 + y + 3) * 134 + px + 3) * 256 + head * 32;
#pragma unroll
      for (int c4 = 0; c4 < 4; ++c4)
        *(bf16x8*)(dst + c4 * 8) = *(const bf16x8*)&Cl[px * 136 + sel * 64 + c4 * 8];
    }
    __syncthreads();
    // ---- Pass B: ClV [o][px] -> V^T row chains ----
    bf16s* ClV = smem;  // stride 132
#pragma unroll
    for (int mi = 0; mi < 4; ++mi)
#pragma unroll
      for (int ni = 0; ni < 4; ++ni)
#pragma unroll
        for (int rg = 0; rg < 4; ++rg) {
          int m = wm * 64 + mi * 16 + g * 4 + rg;
          int n = wn * 64 + ni * 16 + l15;
          ClV[m * 132 + n] = f2b(acc[mi][ni][rg]);
        }
    __syncthreads();
    {
      int vrow = t >> 2, q2 = t & 3;          // 64 V rows x 4 segments
      int hsel = vrow >> 5, d = vrow & 31;
      int o_local = 32 + d + hsel * 64;       // V rows within the tile
      int head = 2 * (mt - 2) + hsel;
      bf16s* gv = v_ws +
          (((size_t)(b * 8 + head) * 32 + d) * 134 + (y + 3)) * 144 + 11 + q2 * 32;
      unsigned int dws[16];                   // 32 bf16 (elements E0..E31)
#pragma unroll
      for (int u = 0; u < 8; ++u) {
        uint2 rr = *(const uint2*)&ClV[o_local * 132 + q2 * 32 + u * 4];
        dws[2 * u] = rr.x;
        dws[2 * u + 1] = rr.y;
      }
      gv[0] = (bf16s)(dws[0] & 0xffffu);      // E0
#pragma unroll
      for (int j = 0; j < 7; ++j) {           // E1..E28
        uint2 w;
        w.x = __builtin_amdgcn_alignbit(dws[2 * j + 1], dws[2 * j], 16);
        w.y = __builtin_amdgcn_alignbit(dws[2 * j + 2], dws[2 * j + 1], 16);
        *(uint2*)(gv + 1 + 4 * j) = w;
      }
      *(unsigned int*)(gv + 29) =             // E29,E30
          __builtin_amdgcn_alignbit(dws[15], dws[14], 16);
      gv[31] = (bf16s)(dws[15] >> 16);        // E31
    }
  }
}

// ---------------------------------------------------------------------------
// K2: attention, S^T form, row-major key' = i*16+j.
// LDS: vT 14336 shared + 4 x 7168 per-wave (RW/RH fp32, then pP bf16).
// Granule-4 XOR swizzle on pP (by q&7) and vT (by d&7) rows kills conflicts.
// PV in O = P.V orientation -> float4 output stores.
// ---------------------------------------------------------------------------
__global__ __launch_bounds__(256, 3) void k_attn(const bf16s* __restrict__ q_ws,
                                                 const bf16s* __restrict__ kv_K,
                                                 const bf16s* __restrict__ v_ws,
                                                 const bf16s* __restrict__ rel_b,
                                                 float* __restrict__ outp) {
  __shared__ __align__(16) char arena[43008];
  bf16s* vT = (bf16s*)arena;                         // [d 32][key' 224] swizzled
  const int t = threadIdx.x;
  const int wv = t >> 6, lane = t & 63, g = lane >> 4, l15 = lane & 15;
  char* pw = arena + 14336 + wv * 7168;              // per-wave private
  float* RWp = (float*)pw;                           // [16 q][34]
  float* RHp = RWp + 544;                            // [16 q][34]
  bf16s* pP  = (bf16s*)pw;                           // [16 q][224] swizzled

  // XCD-aware swizzle
  int wgid = blockIdx.x;
  int xcd = wgid & 7, chnk = wgid >> 3;
  int bxlo = chnk & 3, rest = chnk >> 2;
  int c = xcd * 256 + rest;               // 0..2047
  int bx = (c & 3) * 4 + bxlo;
  int byy = (c >> 2) & 15;
  int bh = c >> 6;                        // 0..31
  int b = bh >> 3, hd = bh & 7;
  int blk = byy * 16 + bx;

  // --- stage vT from global V^T (aligned b64 both ways) ---
  for (int idx = t; idx < 1792; idx += 256) {        // 7 iters exact
    int d = idx / 56, r = idx - d * 56;
    int i = r >> 2, q4 = r & 3;
    uint2 val = *(const uint2*)(v_ws +
        (((size_t)(bh * 32 + d)) * 134 + byy * 8 + i) * 144 + bx * 8 + 8 + q4 * 4);
    *(uint2*)&vT[d * 224 + (((i * 4 + q4) ^ (d & 7)) << 2)] = val;
  }

  // --- per-lane operand fragments straight from global (L2-hot) ---
  const bf16s* qg = q_ws + ((size_t)bh * 256 + blk) * 2048;
  bf16x8 aq = *(const bf16x8*)(qg + (wv * 16 + l15) * 32 + g * 8);   // B: q
  const int jcl = (l15 < 14) ? l15 : 13;
  const bf16s* kbase = kv_K +
      (((size_t)b * 134 + byy * 8) * 134 + bx * 8 + jcl) * 256 + hd * 32 + g * 8;
  bf16x8 kf[14];
#pragma unroll
  for (int nt = 0; nt < 14; ++nt)
    kf[nt] = *(const bf16x8*)(kbase + (size_t)nt * 34304);           // 134*256
  bf16x8 wf[2], hf[2];
#pragma unroll
  for (int t16 = 0; t16 < 2; ++t16) {
    wf[t16] = *(const bf16x8*)(rel_b + (t16 * 16 + l15) * 32 + g * 8);
    hf[t16] = *(const bf16x8*)(rel_b + 1024 + (t16 * 16 + l15) * 32 + g * 8);
  }

  // --- QK^T (S^T): acc[nt] rows = key' nt*16 + g*4+rg (i=nt, j=g*4+rg) ---
  f32x4 acc[14];
#pragma unroll
  for (int nt = 0; nt < 14; ++nt) acc[nt] = (f32x4){0.f, 0.f, 0.f, 0.f};
#pragma unroll
  for (int nt = 0; nt < 14; ++nt) acc[nt] = MFMA16(kf[nt], aq, acc[nt]);

  // --- rel logits: D[r][q], store per-wave tables ---
  {
    f32x4 zz = (f32x4){0.f, 0.f, 0.f, 0.f};
#pragma unroll
    for (int t16 = 0; t16 < 2; ++t16) {
      f32x4 rw = MFMA16(wf[t16], aq, zz);
      f32x4 rh = MFMA16(hf[t16], aq, zz);
#pragma unroll
      for (int rg = 0; rg < 4; ++rg) {
        RWp[l15 * 34 + t16 * 16 + g * 4 + rg] = rw[rg];
        RHp[l15 * 34 + t16 * 16 + g * 4 + rg] = rh[rg];
      }
    }
  }

  // --- softmax (no max-sub; fixed shift). q = wv*16+l15 ---
  const int jq = l15 & 7;
  const int iq = wv * 2 + (l15 >> 3);
  const float* RWr = RWp + l15 * 34;
  const float* RHr = RHp + l15 * 34;
  const int iwb = 13 + g * 4 - jq;
  float wL0 = fmaf(RWr[iwb],     LOG2E, -EXP_SHIFT);
  float wL1 = fmaf(RWr[iwb + 1], LOG2E, -EXP_SHIFT);
  float wL2 = fmaf(RWr[iwb + 2], LOG2E, -EXP_SHIFT);
  float wL3 = fmaf(RWr[iwb + 3], LOG2E, -EXP_SHIFT);
  const float SL = SCALE_QK * LOG2E;
  float sm = 0.f;
#pragma unroll
  for (int nt = 0; nt < 14; ++nt) {
    float hL = RHr[13 + nt - iq] * LOG2E;
    float e0 = __builtin_amdgcn_exp2f(fmaf(acc[nt][0], SL, wL0 + hL));
    float e1 = __builtin_amdgcn_exp2f(fmaf(acc[nt][1], SL, wL1 + hL));
    float e2 = __builtin_amdgcn_exp2f(fmaf(acc[nt][2], SL, wL2 + hL));
    float e3 = __builtin_amdgcn_exp2f(fmaf(acc[nt][3], SL, wL3 + hL));
    if (g == 3) { e2 = 0.f; e3 = 0.f; }   // j = 14,15 invalid
    sm += e0 + e1 + e2 + e3;
    acc[nt][0] = e0; acc[nt][1] = e1; acc[nt][2] = e2; acc[nt][3] = e3;
  }
  sm += __shfl_xor(sm, 16);
  sm += __shfl_xor(sm, 32);
  float rs = __builtin_amdgcn_rcpf(sm);

  // --- P store: pP[q][key'] with granule-4 swizzle by s = q&7 ---
  const int s = l15 & 7;
#pragma unroll
  for (int nt = 0; nt < 14; ++nt) {
    bf16s p0 = f2b(acc[nt][0] * rs), p1 = f2b(acc[nt][1] * rs);
    bf16s p2 = f2b(acc[nt][2] * rs), p3 = f2b(acc[nt][3] * rs);
    unsigned int lo = (unsigned short)p0 | ((unsigned int)(unsigned short)p1 << 16);
    unsigned int hi = (unsigned short)p2 | ((unsigned int)(unsigned short)p3 << 16);
    *(uint2*)(pP + l15 * 224 + (((nt * 4 + g) ^ s) << 2)) = make_uint2(lo, hi);
  }

  __syncthreads();  // vT staged (pP/RW are wave-local)

  // --- PV: O[q][d] = P[q][key] V[key][d]; A=pP rows q, B=vT rows d ---
  f32x4 oa0 = (f32x4){0.f, 0.f, 0.f, 0.f};
  f32x4 oa1 = (f32x4){0.f, 0.f, 0.f, 0.f};
#pragma unroll
  for (int ks = 0; ks < 7; ++ks) {
    int G0 = ks * 8 + g * 2, G1 = G0 + 1;
    uint2 pa = *(const uint2*)(pP + l15 * 224 + ((G0 ^ s) << 2));
    uint2 pb = *(const uint2*)(pP + l15 * 224 + ((G1 ^ s) << 2));
    u32x4 ap4 = {pa.x, pa.y, pb.x, pb.y};
    bf16x8 ap = __builtin_bit_cast(bf16x8, ap4);
    uint2 va = *(const uint2*)(vT + l15 * 224 + ((G0 ^ s) << 2));
    uint2 vb = *(const uint2*)(vT + l15 * 224 + ((G1 ^ s) << 2));
    u32x4 b04 = {va.x, va.y, vb.x, vb.y};
    bf16x8 bv0 = __builtin_bit_cast(bf16x8, b04);
    uint2 vc = *(const uint2*)(vT + (16 + l15) * 224 + ((G0 ^ s) << 2));
    uint2 vd = *(const uint2*)(vT + (16 + l15) * 224 + ((G1 ^ s) << 2));
    u32x4 b14 = {vc.x, vc.y, vd.x, vd.y};
    bf16x8 bv1 = __builtin_bit_cast(bf16x8, b14);
    oa0 = MFMA16(ap, bv0, oa0);
    oa1 = MFMA16(ap, bv1, oa1);
  }

  // --- store: C rows = q (py=wv*2+(g>>1), px=(g&1)*4+rg) -> float4 x2 ---
  {
    size_t base = (((size_t)(b * 256 + hd * 32 + l15) * 128 +
                    byy * 8 + wv * 2 + (g >> 1)) * 128) + bx * 8 + (g & 1) * 4;
    *(float4*)(outp + base) = make_float4(oa0[0], oa0[1], oa0[2], oa0[3]);
    *(float4*)(outp + base + (size_t)16 * 16384) =
        make_float4(oa1[0], oa1[1], oa1[2], oa1[3]);
  }
}

// ---------------------------------------------------------------------------
extern "C" void kernel_launch(void* const* d_in, const int* in_sizes, int n_in,
                              void* d_out, int out_size, void* d_ws, size_t ws_size,
                              hipStream_t stream) {
  (void)in_sizes; (void)n_in; (void)out_size; (void)ws_size;
  const float* x    = (const float*)d_in[0];
  const float* wq   = (const float*)d_in[1];
  const float* wkv  = (const float*)d_in[2];
  const float* hrel = (const float*)d_in[3];
  const float* wrel = (const float*)d_in[4];
  float* outp = (float*)d_out;

  bf16s* xT    = (bf16s*)d_ws;        // 16,777,216
  bf16s* q_ws  = xT + 16777216;       // 16,777,216
  bf16s* kv_K  = q_ws + 16777216;     // 18,386,944  [b][134][134][256]
  bf16s* v_ws  = kv_K + 18386944;     // 19,759,104  [1024][134][144]
  bf16s* wq_b  = v_ws + 19759104;     //     65,536
  bf16s* wkv_b = wq_b + 65536;        //    131,072
  bf16s* rel_b = wkv_b + 131072;      //      2,048

  hipLaunchKernelGGL(k_convert,    dim3(776),       dim3(256), 0, stream,
                     wq, wkv, hrel, wrel, wq_b, wkv_b, rel_b);
  hipLaunchKernelGGL(k_transpose,  dim3(4, 256, 4), dim3(256), 0, stream, x, xT);
  hipLaunchKernelGGL(k_zero_border, dim3(2242),     dim3(256), 0, stream, kv_K, v_ws);
  hipLaunchKernelGGL(k_qkv,        dim3(6, 128, 4), dim3(256), 0, stream,
                     wq_b, wkv_b, xT, q_ws, kv_K, v_ws);
  hipLaunchKernelGGL(k_attn,       dim3(8192),      dim3(256), 0, stream,
                     q_ws, kv_K, v_ws, rel_b, outp);
}